// Round 3
// baseline (283.770 us; speedup 1.0000x reference)
//
#include <hip/hip_runtime.h>
#include <math.h>

#define CH 85

// records per scale
static constexpr int RS = 16 * 76 * 76 * 3;   // 277248 (stride 8)
static constexpr int RM = 16 * 38 * 38 * 3;   //  69312 (stride 16)
static constexpr int RL = 16 * 19 * 19 * 3;   //  17328 (stride 32)

static constexpr int ES = RS * CH, EM = RM * CH, EL = RL * CH;  // elements
static constexpr int FS = ES / 4, FM = EM / 4, FL = EL / 4;     // float4s

static constexpr int CHUNK = 4096;  // float4s per BCE block (16/thread)
static constexpr int NBS = (FS + CHUNK - 1) / CHUNK;   // 1439
static constexpr int NBM = (FM + CHUNK - 1) / CHUNK;   // 360
static constexpr int NBL = (FL + CHUNK - 1) / CHUNK;   // 90
static constexpr int NBCE = NBS + NBM + NBL;           // 1889

static constexpr int QS = RS / 256;          // 1083 (exact)
static constexpr int QM = (RM + 255) / 256;  // 271
static constexpr int QL = (RL + 255) / 256;  // 68
static constexpr int NQ = QS + QM + QL;      // 1422

static constexpr int NBLK = NBCE + NQ;       // 3311

__constant__ float c_anchors[18] = {
    12.f, 16.f, 19.f, 36.f, 40.f, 28.f,
    36.f, 75.f, 76.f, 55.f, 72.f, 146.f,
    142.f, 110.f, 192.f, 243.f, 459.f, 401.f
};

__device__ __forceinline__ float fast_rcp(float x) { return __builtin_amdgcn_rcpf(x); }
__device__ __forceinline__ float sigm(float x)     { return fast_rcp(1.f + __expf(-x)); }
__device__ __forceinline__ float softplusf(float x) {
    return fmaxf(x, 0.f) + __logf(1.f + __expf(-fabsf(x)));
}

// ws layout: [0,NQ) ciou | [NQ,2NQ) conf | [2NQ,2NQ+NBCE) prob
__global__ __launch_bounds__(256) void yolo_main(
    const float* __restrict__ conv_l, const float* __restrict__ conv_m,
    const float* __restrict__ conv_s, const float* __restrict__ lab_s,
    const float* __restrict__ lab_m, const float* __restrict__ lab_l,
    const float* __restrict__ tb, float* __restrict__ pb)
{
    int blk = blockIdx.x;

    if (blk < NBCE) {
        // ================= BCE streaming block =================
        const float* cbase; const float* lbase; int E; int q;
        if (blk < NBS)            { q = blk;              cbase = conv_s; lbase = lab_s; E = ES; }
        else if (blk < NBS + NBM) { q = blk - NBS;        cbase = conv_m; lbase = lab_m; E = EM; }
        else                      { q = blk - NBS - NBM;  cbase = conv_l; lbase = lab_l; E = EL; }

        int e = (q * CHUNK + (int)threadIdx.x) * 4;   // element index of my first f4
        unsigned r = (unsigned)e / 85u;
        unsigned c = (unsigned)e - r * 85u;

        float acc = 0.f;

        #pragma unroll
        for (int g = 0; g < 4; ++g) {
            float4 cv[4], lv[4];
            float  rsp[4];
            unsigned cc[4];
            int eloc = e; unsigned rr = r, ch = c;
            #pragma unroll
            for (int it = 0; it < 4; ++it) {
                cc[it] = ch;
                if (eloc < E) {
                    cv[it]  = *reinterpret_cast<const float4*>(cbase + eloc);
                    lv[it]  = *reinterpret_cast<const float4*>(lbase + eloc);
                    rsp[it] = lbase[rr * 85u + 4u];
                } else {
                    cv[it] = make_float4(0.f, 0.f, 0.f, 0.f);
                    lv[it] = make_float4(0.f, 0.f, 0.f, 0.f);
                    rsp[it] = 0.f;
                }
                eloc += 1024; rr += 12u; ch += 4u;
                if (ch >= 85u) { ch -= 85u; ++rr; }
            }
            e = eloc; r = rr; c = ch;

            #pragma unroll
            for (int it = 0; it < 4; ++it) {
                float xs[4] = {cv[it].x, cv[it].y, cv[it].z, cv[it].w};
                float ls[4] = {lv[it].x, lv[it].y, lv[it].z, lv[it].w};
                #pragma unroll
                for (int d = 0; d < 4; ++d) {
                    unsigned cd = cc[it] + (unsigned)d;
                    float w = (cd - 5u < 80u) ? rsp[it] : 0.f;  // ch in [5,85) of record rr
                    float x = xs[d], l = ls[d];
                    acc = fmaf(w, softplusf(x) - l * x, acc);   // l*(-log p)+(1-l)*(-log(1-p))
                }
            }
        }

        // block reduce 1 value
        for (int off = 32; off > 0; off >>= 1) acc += __shfl_down(acc, off);
        __shared__ float red[4];
        int lane = threadIdx.x & 63, wv = threadIdx.x >> 6;
        if (lane == 0) red[wv] = acc;
        __syncthreads();
        if (threadIdx.x == 0)
            pb[2 * NQ + blk] = red[0] + red[1] + red[2] + red[3];

    } else {
        // ================= box / conf block =================
        int qb = blk - NBCE;
        const float* conv; const float* lab;
        int S; float stride; int ao; int r0; int nrec_scale;
        if (qb < QS)           { conv = conv_s; lab = lab_s; S = 76; stride = 8.f;  ao = 0;  r0 = qb * 256;              nrec_scale = RS; }
        else if (qb < QS + QM) { conv = conv_m; lab = lab_m; S = 38; stride = 16.f; ao = 6;  r0 = (qb - QS) * 256;       nrec_scale = RM; }
        else                   { conv = conv_l; lab = lab_l; S = 19; stride = 32.f; ao = 12; r0 = (qb - QS - QM) * 256;  nrec_scale = RL; }

        float ciou_acc = 0.f, conf_acc = 0.f;
        int t = threadIdx.x;
        int rec = r0 + t;
        if (rec < nrec_scale) {
            unsigned rl = (unsigned)rec;
            unsigned a = rl % 3u; unsigned qq = rl / 3u;
            unsigned j = qq % (unsigned)S; qq /= (unsigned)S;
            unsigned i = qq % (unsigned)S; unsigned b = qq / (unsigned)S;

            const float* cp = conv + (size_t)rec * CH;
            const float* lp = lab  + (size_t)rec * CH;
            float c0 = cp[0], c1 = cp[1], c2v = cp[2], c3 = cp[3], c4 = cp[4];
            float lx = lp[0], ly = lp[1], lw = lp[2], lh = lp[3], resp = lp[4];

            // decode
            float px = (sigm(c0) + (float)j) * stride;
            float py = (sigm(c1) + (float)i) * stride;
            float pw = __expf(c2v) * c_anchors[ao + 2 * a];
            float ph = __expf(c3)  * c_anchors[ao + 2 * a + 1];

            // CIoU vs label
            float hx = 0.5f * pw, hy = 0.5f * ph;
            float b1x1 = px - hx, b1y1 = py - hy, b1x2 = px + hx, b1y2 = py + hy;
            float hlx = 0.5f * lw, hly = 0.5f * lh;
            float b2x1 = lx - hlx, b2y1 = ly - hly, b2x2 = lx + hlx, b2y2 = ly + hly;

            float area1 = (b1x2 - b1x1) * (b1y2 - b1y1);
            float area2 = (b2x2 - b2x1) * (b2y2 - b2y1);
            float lux = fmaxf(b1x1, b2x1), luy = fmaxf(b1y1, b2y1);
            float rdx = fminf(b1x2, b2x2), rdy = fminf(b1y2, b2y2);
            float iw = fmaxf(rdx - lux, 0.f), ih = fmaxf(rdy - luy, 0.f);
            float inter = iw * ih;
            float uni = area1 + area2 - inter;
            float iou = inter / (uni + 1e-9f);

            float encw = fmaxf(b1x2, b2x2) - fminf(b1x1, b2x1);
            float ench = fmaxf(b1y2, b2y2) - fminf(b1y1, b2y1);
            float cc2 = encw * encw + ench * ench;
            float dx = px - lx, dy = py - ly;
            float p2 = dx * dx + dy * dy;
            float at1 = atanf(pw / (ph + 1e-9f));
            float at2 = atanf(lw / (lh + 1e-9f));
            float dat = at1 - at2;
            const float FOUR_OVER_PI2 = 0.40528473456935109f;  // 4/pi^2
            float v = FOUR_OVER_PI2 * dat * dat;
            float al = v / (1.f - iou + v);
            float ciou = iou - p2 / cc2 - al * v;
            float bscale = 2.f - lw * lh * (1.f / (608.f * 608.f));
            ciou_acc = resp * bscale * (1.f - ciou);

            // conf loss: max IoU vs 70 true boxes of image b
            const float* tbp = tb + (size_t)b * 70 * 4;
            float parea = pw * ph;
            float maxiou = 0.f;
            for (int n = 0; n < 70; n++) {
                float tx = tbp[4 * n], ty = tbp[4 * n + 1];
                float tw = tbp[4 * n + 2], th = tbp[4 * n + 3];
                float tx1 = tx - 0.5f * tw, ty1 = ty - 0.5f * th;
                float tx2 = tx + 0.5f * tw, ty2 = ty + 0.5f * th;
                float ix1 = fmaxf(b1x1, tx1), iy1 = fmaxf(b1y1, ty1);
                float ix2 = fminf(b1x2, tx2), iy2 = fminf(b1y2, ty2);
                float iiw = fmaxf(ix2 - ix1, 0.f), iih = fmaxf(iy2 - iy1, 0.f);
                float ia = iiw * iih;
                float u = parea + tw * th - ia;
                maxiou = fmaxf(maxiou, ia * fast_rcp(u));
            }
            float rbgd = (1.f - resp) * (maxiou < 0.5f ? 1.f : 0.f);
            float spc = softplusf(c4);
            conf_acc = resp * (spc - c4) + rbgd * spc;
        }

        for (int off = 32; off > 0; off >>= 1) {
            ciou_acc += __shfl_down(ciou_acc, off);
            conf_acc += __shfl_down(conf_acc, off);
        }
        __shared__ float red2[4][2];
        int lane = threadIdx.x & 63, wv = threadIdx.x >> 6;
        if (lane == 0) { red2[wv][0] = ciou_acc; red2[wv][1] = conf_acc; }
        __syncthreads();
        if (threadIdx.x == 0) {
            pb[qb]      = red2[0][0] + red2[1][0] + red2[2][0] + red2[3][0];
            pb[NQ + qb] = red2[0][1] + red2[1][1] + red2[2][1] + red2[3][1];
        }
    }
}

__global__ __launch_bounds__(256) void finalize_k(const float* __restrict__ pb,
                                                  float* __restrict__ out)
{
    double s0 = 0.0, s1 = 0.0, s2 = 0.0;
    for (int i = threadIdx.x; i < NQ; i += 256) {
        s0 += (double)pb[i];
        s1 += (double)pb[NQ + i];
    }
    for (int i = threadIdx.x; i < NBCE; i += 256) {
        s2 += (double)pb[2 * NQ + i];
    }
    for (int off = 32; off > 0; off >>= 1) {
        s0 += __shfl_down(s0, off);
        s1 += __shfl_down(s1, off);
        s2 += __shfl_down(s2, off);
    }
    __shared__ double rd[4][3];
    int lane = threadIdx.x & 63, wv = threadIdx.x >> 6;
    if (lane == 0) { rd[wv][0] = s0; rd[wv][1] = s1; rd[wv][2] = s2; }
    __syncthreads();
    if (threadIdx.x == 0) {
        float ci = (float)((rd[0][0] + rd[1][0] + rd[2][0] + rd[3][0]) / 16.0);
        float co = (float)((rd[0][1] + rd[1][1] + rd[2][1] + rd[3][1]) / 16.0);
        float pr = (float)((rd[0][2] + rd[1][2] + rd[2][2] + rd[3][2]) / 16.0);
        out[0] = ci + co + pr;
        out[1] = ci;
        out[2] = co;
        out[3] = pr;
    }
}

extern "C" void kernel_launch(void* const* d_in, const int* in_sizes, int n_in,
                              void* d_out, int out_size, void* d_ws, size_t ws_size,
                              hipStream_t stream) {
    const float* conv_l = (const float*)d_in[0];
    const float* conv_m = (const float*)d_in[1];
    const float* conv_s = (const float*)d_in[2];
    const float* lab_s  = (const float*)d_in[3];
    const float* lab_m  = (const float*)d_in[4];
    const float* lab_l  = (const float*)d_in[5];
    const float* tb     = (const float*)d_in[6];
    float* pb  = (float*)d_ws;   // 2*NQ + NBCE floats
    float* out = (float*)d_out;

    yolo_main<<<NBLK, 256, 0, stream>>>(conv_l, conv_m, conv_s,
                                        lab_s, lab_m, lab_l, tb, pb);
    finalize_k<<<1, 256, 0, stream>>>(pb, out);
}

// Round 4
// 279.040 us; speedup vs baseline: 1.0170x; 1.0170x over previous
//
#include <hip/hip_runtime.h>
#include <math.h>

#define CH 85

// records per scale
static constexpr int RS = 16 * 76 * 76 * 3;   // 277248 (stride 8)
static constexpr int RM = 16 * 38 * 38 * 3;   //  69312 (stride 16)
static constexpr int RL = 16 * 19 * 19 * 3;   //  17328 (stride 32)

static constexpr int ES = RS * CH, EM = RM * CH, EL = RL * CH;  // elements
static constexpr int FS = ES / 4, FM = EM / 4, FL = EL / 4;     // float4 counts

static constexpr int CHUNK = 8192;  // float4s per BCE block (32/thread)
static constexpr int NBS = (FS + CHUNK - 1) / CHUNK;   // 720
static constexpr int NBM = (FM + CHUNK - 1) / CHUNK;   // 180
static constexpr int NBL = (FL + CHUNK - 1) / CHUNK;   // 45
static constexpr int NBCE = NBS + NBM + NBL;           // 945

static constexpr int QS = RS / 256;          // 1083 (exact)
static constexpr int QM = (RM + 255) / 256;  // 271
static constexpr int QL = (RL + 255) / 256;  // 68
static constexpr int NQ = QS + QM + QL;      // 1422

static constexpr int NBLK = NBCE + NQ;       // 2367

__constant__ float c_anchors[18] = {
    12.f, 16.f, 19.f, 36.f, 40.f, 28.f,
    36.f, 75.f, 76.f, 55.f, 72.f, 146.f,
    142.f, 110.f, 192.f, 243.f, 459.f, 401.f
};

__device__ __forceinline__ float fast_rcp(float x) { return __builtin_amdgcn_rcpf(x); }
__device__ __forceinline__ float sigm(float x)     { return fast_rcp(1.f + __expf(-x)); }
__device__ __forceinline__ float softplusf(float x) {
    return fmaxf(x, 0.f) + __logf(1.f + __expf(-fabsf(x)));
}

// ws layout: [0,NQ) ciou | [NQ,2NQ) conf | [2NQ,2NQ+NBCE) prob
__global__ __launch_bounds__(256) void yolo_main(
    const float* __restrict__ conv_l, const float* __restrict__ conv_m,
    const float* __restrict__ conv_s, const float* __restrict__ lab_s,
    const float* __restrict__ lab_m, const float* __restrict__ lab_l,
    const float* __restrict__ tb, float* __restrict__ pb)
{
    int blk = blockIdx.x;

    if (blk < NBCE) {
        // ================= BCE streaming block =================
        const float* cbase; const float* lbase; int E; int q;
        if (blk < NBS)            { q = blk;              cbase = conv_s; lbase = lab_s; E = ES; }
        else if (blk < NBS + NBM) { q = blk - NBS;        cbase = conv_m; lbase = lab_m; E = EM; }
        else                      { q = blk - NBS - NBM;  cbase = conv_l; lbase = lab_l; E = EL; }

        // block's record span -> resp table in LDS
        int e_first = q * (CHUNK * 4);
        int e_lastp = min(E, e_first + CHUNK * 4);       // exclusive
        unsigned rf = (unsigned)e_first / 85u;
        unsigned rl = (unsigned)(e_lastp - 1) / 85u;     // inclusive
        int nrec_blk = (int)(rl - rf) + 1;               // <= 387

        __shared__ float s_resp[388];
        for (int t = threadIdx.x; t < nrec_blk; t += 256)
            s_resp[t] = lbase[(size_t)(rf + (unsigned)t) * 85u + 4u];
        __syncthreads();

        int f40 = q * CHUNK + (int)threadIdx.x;
        float acc = 0.f;

        #pragma unroll
        for (int g = 0; g < 8; ++g) {
            float4 cv[4], lv[4];
            unsigned rr[4], cc[4], vld[4];
            #pragma unroll
            for (int u = 0; u < 4; ++u) {
                int e = (f40 + (g * 4 + u) * 256) << 2;
                vld[u] = (e < E) ? 1u : 0u;
                int es = min(e, E - 4);                  // clamp: always in-bounds
                cv[u] = *reinterpret_cast<const float4*>(cbase + es);
                lv[u] = *reinterpret_cast<const float4*>(lbase + es);
                unsigned r = (unsigned)es / 85u;         // compiler magic-div
                rr[u] = r; cc[u] = (unsigned)es - r * 85u;
            }
            #pragma unroll
            for (int u = 0; u < 4; ++u) {
                float resp = s_resp[rr[u] - rf];
                resp = vld[u] ? resp : 0.f;
                float xs[4] = {cv[u].x, cv[u].y, cv[u].z, cv[u].w};
                float ls[4] = {lv[u].x, lv[u].y, lv[u].z, lv[u].w};
                #pragma unroll
                for (int d = 0; d < 4; ++d) {
                    // element belongs to record rr[u] channel cc[u]+d (wrap -> ch<5 of next record -> weight 0)
                    float w = (cc[u] + (unsigned)d - 5u < 80u) ? resp : 0.f;
                    acc = fmaf(w, softplusf(xs[d]) - ls[d] * xs[d], acc);
                }
            }
        }

        for (int off = 32; off > 0; off >>= 1) acc += __shfl_down(acc, off);
        __shared__ float red[4];
        int lane = threadIdx.x & 63, wv = threadIdx.x >> 6;
        if (lane == 0) red[wv] = acc;
        __syncthreads();
        if (threadIdx.x == 0)
            pb[2 * NQ + blk] = red[0] + red[1] + red[2] + red[3];

    } else {
        // ================= box / conf block =================
        int qb = blk - NBCE;
        const float* conv; const float* lab;
        int S; float stride; int ao; int r0; int nrec_scale;
        if (qb < QS)           { conv = conv_s; lab = lab_s; S = 76; stride = 8.f;  ao = 0;  r0 = qb * 256;              nrec_scale = RS; }
        else if (qb < QS + QM) { conv = conv_m; lab = lab_m; S = 38; stride = 16.f; ao = 6;  r0 = (qb - QS) * 256;       nrec_scale = RM; }
        else                   { conv = conv_l; lab = lab_l; S = 19; stride = 32.f; ao = 12; r0 = (qb - QS - QM) * 256;  nrec_scale = RL; }

        float ciou_acc = 0.f, conf_acc = 0.f;
        int rec = r0 + (int)threadIdx.x;
        if (rec < nrec_scale) {
            unsigned rl2 = (unsigned)rec;
            unsigned a = rl2 % 3u; unsigned qq = rl2 / 3u;
            unsigned j = qq % (unsigned)S; qq /= (unsigned)S;
            unsigned i = qq % (unsigned)S; unsigned b = qq / (unsigned)S;

            const float* cp = conv + (size_t)rec * CH;
            const float* lp = lab  + (size_t)rec * CH;
            float c0 = cp[0], c1 = cp[1], c2v = cp[2], c3 = cp[3], c4 = cp[4];
            float lx = lp[0], ly = lp[1], lw = lp[2], lh = lp[3], resp = lp[4];

            float px = (sigm(c0) + (float)j) * stride;
            float py = (sigm(c1) + (float)i) * stride;
            float pw = __expf(c2v) * c_anchors[ao + 2 * a];
            float ph = __expf(c3)  * c_anchors[ao + 2 * a + 1];

            float hx = 0.5f * pw, hy = 0.5f * ph;
            float b1x1 = px - hx, b1y1 = py - hy, b1x2 = px + hx, b1y2 = py + hy;
            float hlx = 0.5f * lw, hly = 0.5f * lh;
            float b2x1 = lx - hlx, b2y1 = ly - hly, b2x2 = lx + hlx, b2y2 = ly + hly;

            float area1 = (b1x2 - b1x1) * (b1y2 - b1y1);
            float area2 = (b2x2 - b2x1) * (b2y2 - b2y1);
            float lux = fmaxf(b1x1, b2x1), luy = fmaxf(b1y1, b2y1);
            float rdx = fminf(b1x2, b2x2), rdy = fminf(b1y2, b2y2);
            float iw = fmaxf(rdx - lux, 0.f), ih = fmaxf(rdy - luy, 0.f);
            float inter = iw * ih;
            float uni = area1 + area2 - inter;
            float iou = inter / (uni + 1e-9f);

            float encw = fmaxf(b1x2, b2x2) - fminf(b1x1, b2x1);
            float ench = fmaxf(b1y2, b2y2) - fminf(b1y1, b2y1);
            float cc2 = encw * encw + ench * ench;
            float dx = px - lx, dy = py - ly;
            float p2 = dx * dx + dy * dy;
            float at1 = atanf(pw / (ph + 1e-9f));
            float at2 = atanf(lw / (lh + 1e-9f));
            float dat = at1 - at2;
            const float FOUR_OVER_PI2 = 0.40528473456935109f;  // 4/pi^2
            float v = FOUR_OVER_PI2 * dat * dat;
            float al = v / (1.f - iou + v);
            float ciou = iou - p2 / cc2 - al * v;
            float bscale = 2.f - lw * lh * (1.f / (608.f * 608.f));
            ciou_acc = resp * bscale * (1.f - ciou);

            const float* tbp = tb + (size_t)b * 70 * 4;
            float parea = pw * ph;
            float maxiou = 0.f;
            for (int n = 0; n < 70; n++) {
                float tx = tbp[4 * n], ty = tbp[4 * n + 1];
                float tw = tbp[4 * n + 2], th = tbp[4 * n + 3];
                float tx1 = tx - 0.5f * tw, ty1 = ty - 0.5f * th;
                float tx2 = tx + 0.5f * tw, ty2 = ty + 0.5f * th;
                float ix1 = fmaxf(b1x1, tx1), iy1 = fmaxf(b1y1, ty1);
                float ix2 = fminf(b1x2, tx2), iy2 = fminf(b1y2, ty2);
                float iiw = fmaxf(ix2 - ix1, 0.f), iih = fmaxf(iy2 - iy1, 0.f);
                float ia = iiw * iih;
                float u = parea + tw * th - ia;
                maxiou = fmaxf(maxiou, ia * fast_rcp(u));
            }
            float rbgd = (1.f - resp) * (maxiou < 0.5f ? 1.f : 0.f);
            float spc = softplusf(c4);
            conf_acc = resp * (spc - c4) + rbgd * spc;
        }

        for (int off = 32; off > 0; off >>= 1) {
            ciou_acc += __shfl_down(ciou_acc, off);
            conf_acc += __shfl_down(conf_acc, off);
        }
        __shared__ float red2[4][2];
        int lane = threadIdx.x & 63, wv = threadIdx.x >> 6;
        if (lane == 0) { red2[wv][0] = ciou_acc; red2[wv][1] = conf_acc; }
        __syncthreads();
        if (threadIdx.x == 0) {
            pb[qb]      = red2[0][0] + red2[1][0] + red2[2][0] + red2[3][0];
            pb[NQ + qb] = red2[0][1] + red2[1][1] + red2[2][1] + red2[3][1];
        }
    }
}

__global__ __launch_bounds__(256) void finalize_k(const float* __restrict__ pb,
                                                  float* __restrict__ out)
{
    double s0 = 0.0, s1 = 0.0, s2 = 0.0;
    for (int i = threadIdx.x; i < NQ; i += 256) {
        s0 += (double)pb[i];
        s1 += (double)pb[NQ + i];
    }
    for (int i = threadIdx.x; i < NBCE; i += 256) {
        s2 += (double)pb[2 * NQ + i];
    }
    for (int off = 32; off > 0; off >>= 1) {
        s0 += __shfl_down(s0, off);
        s1 += __shfl_down(s1, off);
        s2 += __shfl_down(s2, off);
    }
    __shared__ double rd[4][3];
    int lane = threadIdx.x & 63, wv = threadIdx.x >> 6;
    if (lane == 0) { rd[wv][0] = s0; rd[wv][1] = s1; rd[wv][2] = s2; }
    __syncthreads();
    if (threadIdx.x == 0) {
        float ci = (float)((rd[0][0] + rd[1][0] + rd[2][0] + rd[3][0]) / 16.0);
        float co = (float)((rd[0][1] + rd[1][1] + rd[2][1] + rd[3][1]) / 16.0);
        float pr = (float)((rd[0][2] + rd[1][2] + rd[2][2] + rd[3][2]) / 16.0);
        out[0] = ci + co + pr;
        out[1] = ci;
        out[2] = co;
        out[3] = pr;
    }
}

extern "C" void kernel_launch(void* const* d_in, const int* in_sizes, int n_in,
                              void* d_out, int out_size, void* d_ws, size_t ws_size,
                              hipStream_t stream) {
    const float* conv_l = (const float*)d_in[0];
    const float* conv_m = (const float*)d_in[1];
    const float* conv_s = (const float*)d_in[2];
    const float* lab_s  = (const float*)d_in[3];
    const float* lab_m  = (const float*)d_in[4];
    const float* lab_l  = (const float*)d_in[5];
    const float* tb     = (const float*)d_in[6];
    float* pb  = (float*)d_ws;   // 2*NQ + NBCE floats
    float* out = (float*)d_out;

    yolo_main<<<NBLK, 256, 0, stream>>>(conv_l, conv_m, conv_s,
                                        lab_s, lab_m, lab_l, tb, pb);
    finalize_k<<<1, 256, 0, stream>>>(pb, out);
}

// Round 5
// 278.213 us; speedup vs baseline: 1.0200x; 1.0030x over previous
//
#include <hip/hip_runtime.h>
#include <math.h>

#define CH 85

// records per scale
static constexpr int RS = 16 * 76 * 76 * 3;   // 277248 (stride 8)
static constexpr int RM = 16 * 38 * 38 * 3;   //  69312 (stride 16)
static constexpr int RL = 16 * 19 * 19 * 3;   //  17328 (stride 32)

static constexpr int ES = RS * CH, EM = RM * CH, EL = RL * CH;  // elements
static constexpr int FS = ES / 4, FM = EM / 4, FL = EL / 4;     // float4 counts

static constexpr int CHUNK = 8192;  // float4s per BCE block (32/thread = 4 groups x 8)
static constexpr int NBS = (FS + CHUNK - 1) / CHUNK;   // 720
static constexpr int NBM = (FM + CHUNK - 1) / CHUNK;   // 180
static constexpr int NBL = (FL + CHUNK - 1) / CHUNK;   // 45
static constexpr int NBCE = NBS + NBM + NBL;           // 945

static constexpr int QS = RS / 256;          // 1083 (exact)
static constexpr int QM = (RM + 255) / 256;  // 271
static constexpr int QL = (RL + 255) / 256;  // 68
static constexpr int NQ = QS + QM + QL;      // 1422

static constexpr int NBLK = NBCE + NQ;       // 2367

__constant__ float c_anchors[18] = {
    12.f, 16.f, 19.f, 36.f, 40.f, 28.f,
    36.f, 75.f, 76.f, 55.f, 72.f, 146.f,
    142.f, 110.f, 192.f, 243.f, 459.f, 401.f
};

typedef float f4v __attribute__((ext_vector_type(4)));

__device__ __forceinline__ f4v ntld(const float* p) {
    return __builtin_nontemporal_load(reinterpret_cast<const f4v*>(p));
}
__device__ __forceinline__ float fast_rcp(float x) { return __builtin_amdgcn_rcpf(x); }
__device__ __forceinline__ float sigm(float x)     { return fast_rcp(1.f + __expf(-x)); }
__device__ __forceinline__ float softplusf(float x) {
    return fmaxf(x, 0.f) + __logf(1.f + __expf(-fabsf(x)));
}

// ws layout: [0,NQ) ciou | [NQ,2NQ) conf | [2NQ,2NQ+NBCE) prob
__global__ __launch_bounds__(256) void yolo_main(
    const float* __restrict__ conv_l, const float* __restrict__ conv_m,
    const float* __restrict__ conv_s, const float* __restrict__ lab_s,
    const float* __restrict__ lab_m, const float* __restrict__ lab_l,
    const float* __restrict__ tb, float* __restrict__ pb)
{
    int blk = blockIdx.x;

    if (blk < NBCE) {
        // ================= BCE streaming block =================
        const float* cbase; const float* lbase; int E; int q;
        if (blk < NBS)            { q = blk;              cbase = conv_s; lbase = lab_s; E = ES; }
        else if (blk < NBS + NBM) { q = blk - NBS;        cbase = conv_m; lbase = lab_m; E = EM; }
        else                      { q = blk - NBS - NBM;  cbase = conv_l; lbase = lab_l; E = EL; }

        // block's record span -> resp table in LDS
        int e_first = q * (CHUNK * 4);
        int e_lastp = min(E, e_first + CHUNK * 4);       // exclusive
        unsigned rf = (unsigned)e_first / 85u;
        unsigned rl = (unsigned)(e_lastp - 1) / 85u;     // inclusive
        int nrec_blk = (int)(rl - rf) + 1;               // <= 387

        __shared__ float s_resp[388];
        for (int t = threadIdx.x; t < nrec_blk; t += 256)
            s_resp[t] = lbase[(size_t)(rf + (unsigned)t) * 85u + 4u];
        __syncthreads();

        int base = q * CHUNK + (int)threadIdx.x;   // my f4 slot, groups step by 256
        float acc = 0.f;

        f4v ca[8], lA[8], cb[8], lB[8];

#define ISSUE(g, cd, ld)                                          \
        _Pragma("unroll")                                         \
        for (int u = 0; u < 8; ++u) {                             \
            int e  = (base + ((g) * 8 + u) * 256) << 2;           \
            int es = min(e, E - 4);                               \
            cd[u] = ntld(cbase + es);                             \
            ld[u] = ntld(lbase + es);                             \
        }

#define COMPUTE(g, cd, ld)                                        \
        _Pragma("unroll")                                         \
        for (int u = 0; u < 8; ++u) {                             \
            int e  = (base + ((g) * 8 + u) * 256) << 2;           \
            int es = min(e, E - 4);                               \
            unsigned r = (unsigned)es / 85u;                      \
            unsigned c = (unsigned)es - r * 85u;                  \
            float resp = s_resp[r - rf];                          \
            resp = (e < E) ? resp : 0.f;                          \
            _Pragma("unroll")                                     \
            for (int d = 0; d < 4; ++d) {                         \
                float w = (c + (unsigned)d - 5u < 80u) ? resp : 0.f; \
                float x = cd[u][d], l = ld[u][d];                 \
                acc = fmaf(w, softplusf(x) - l * x, acc);         \
            }                                                     \
        }

        ISSUE(0, ca, lA)
        ISSUE(1, cb, lB)
        COMPUTE(0, ca, lA)     // waits only on group 0 (16 newer loads outstanding)
        ISSUE(2, ca, lA)       // refill freed buffer
        COMPUTE(1, cb, lB)
        ISSUE(3, cb, lB)
        COMPUTE(2, ca, lA)
        COMPUTE(3, cb, lB)

#undef ISSUE
#undef COMPUTE

        for (int off = 32; off > 0; off >>= 1) acc += __shfl_down(acc, off);
        __shared__ float red[4];
        int lane = threadIdx.x & 63, wv = threadIdx.x >> 6;
        if (lane == 0) red[wv] = acc;
        __syncthreads();
        if (threadIdx.x == 0)
            pb[2 * NQ + blk] = red[0] + red[1] + red[2] + red[3];

    } else {
        // ================= box / conf block =================
        int qb = blk - NBCE;
        const float* conv; const float* lab;
        int S; float stride; int ao; int r0; int nrec_scale;
        if (qb < QS)           { conv = conv_s; lab = lab_s; S = 76; stride = 8.f;  ao = 0;  r0 = qb * 256;              nrec_scale = RS; }
        else if (qb < QS + QM) { conv = conv_m; lab = lab_m; S = 38; stride = 16.f; ao = 6;  r0 = (qb - QS) * 256;       nrec_scale = RM; }
        else                   { conv = conv_l; lab = lab_l; S = 19; stride = 32.f; ao = 12; r0 = (qb - QS - QM) * 256;  nrec_scale = RL; }

        float ciou_acc = 0.f, conf_acc = 0.f;
        int rec = r0 + (int)threadIdx.x;
        if (rec < nrec_scale) {
            unsigned rl2 = (unsigned)rec;
            unsigned a = rl2 % 3u; unsigned qq = rl2 / 3u;
            unsigned j = qq % (unsigned)S; qq /= (unsigned)S;
            unsigned i = qq % (unsigned)S; unsigned b = qq / (unsigned)S;

            const float* cp = conv + (size_t)rec * CH;
            const float* lp = lab  + (size_t)rec * CH;
            float c0 = cp[0], c1 = cp[1], c2v = cp[2], c3 = cp[3], c4 = cp[4];
            float lx = lp[0], ly = lp[1], lw = lp[2], lh = lp[3], resp = lp[4];

            float px = (sigm(c0) + (float)j) * stride;
            float py = (sigm(c1) + (float)i) * stride;
            float pw = __expf(c2v) * c_anchors[ao + 2 * a];
            float ph = __expf(c3)  * c_anchors[ao + 2 * a + 1];

            float hx = 0.5f * pw, hy = 0.5f * ph;
            float b1x1 = px - hx, b1y1 = py - hy, b1x2 = px + hx, b1y2 = py + hy;
            float hlx = 0.5f * lw, hly = 0.5f * lh;
            float b2x1 = lx - hlx, b2y1 = ly - hly, b2x2 = lx + hlx, b2y2 = ly + hly;

            float area1 = (b1x2 - b1x1) * (b1y2 - b1y1);
            float area2 = (b2x2 - b2x1) * (b2y2 - b2y1);
            float lux = fmaxf(b1x1, b2x1), luy = fmaxf(b1y1, b2y1);
            float rdx = fminf(b1x2, b2x2), rdy = fminf(b1y2, b2y2);
            float iw = fmaxf(rdx - lux, 0.f), ih = fmaxf(rdy - luy, 0.f);
            float inter = iw * ih;
            float uni = area1 + area2 - inter;
            float iou = inter / (uni + 1e-9f);

            float encw = fmaxf(b1x2, b2x2) - fminf(b1x1, b2x1);
            float ench = fmaxf(b1y2, b2y2) - fminf(b1y1, b2y1);
            float cc2 = encw * encw + ench * ench;
            float dx = px - lx, dy = py - ly;
            float p2 = dx * dx + dy * dy;
            float at1 = atanf(pw / (ph + 1e-9f));
            float at2 = atanf(lw / (lh + 1e-9f));
            float dat = at1 - at2;
            const float FOUR_OVER_PI2 = 0.40528473456935109f;  // 4/pi^2
            float v = FOUR_OVER_PI2 * dat * dat;
            float al = v / (1.f - iou + v);
            float ciou = iou - p2 / cc2 - al * v;
            float bscale = 2.f - lw * lh * (1.f / (608.f * 608.f));
            ciou_acc = resp * bscale * (1.f - ciou);

            const float* tbp = tb + (size_t)b * 70 * 4;
            float parea = pw * ph;
            float maxiou = 0.f;
            for (int n = 0; n < 70; n++) {
                float tx = tbp[4 * n], ty = tbp[4 * n + 1];
                float tw = tbp[4 * n + 2], th = tbp[4 * n + 3];
                float tx1 = tx - 0.5f * tw, ty1 = ty - 0.5f * th;
                float tx2 = tx + 0.5f * tw, ty2 = ty + 0.5f * th;
                float ix1 = fmaxf(b1x1, tx1), iy1 = fmaxf(b1y1, ty1);
                float ix2 = fminf(b1x2, tx2), iy2 = fminf(b1y2, ty2);
                float iiw = fmaxf(ix2 - ix1, 0.f), iih = fmaxf(iy2 - iy1, 0.f);
                float ia = iiw * iih;
                float u = parea + tw * th - ia;
                maxiou = fmaxf(maxiou, ia * fast_rcp(u));
            }
            float rbgd = (1.f - resp) * (maxiou < 0.5f ? 1.f : 0.f);
            float spc = softplusf(c4);
            conf_acc = resp * (spc - c4) + rbgd * spc;
        }

        for (int off = 32; off > 0; off >>= 1) {
            ciou_acc += __shfl_down(ciou_acc, off);
            conf_acc += __shfl_down(conf_acc, off);
        }
        __shared__ float red2[4][2];
        int lane = threadIdx.x & 63, wv = threadIdx.x >> 6;
        if (lane == 0) { red2[wv][0] = ciou_acc; red2[wv][1] = conf_acc; }
        __syncthreads();
        if (threadIdx.x == 0) {
            pb[qb]      = red2[0][0] + red2[1][0] + red2[2][0] + red2[3][0];
            pb[NQ + qb] = red2[0][1] + red2[1][1] + red2[2][1] + red2[3][1];
        }
    }
}

__global__ __launch_bounds__(256) void finalize_k(const float* __restrict__ pb,
                                                  float* __restrict__ out)
{
    double s0 = 0.0, s1 = 0.0, s2 = 0.0;
    for (int i = threadIdx.x; i < NQ; i += 256) {
        s0 += (double)pb[i];
        s1 += (double)pb[NQ + i];
    }
    for (int i = threadIdx.x; i < NBCE; i += 256) {
        s2 += (double)pb[2 * NQ + i];
    }
    for (int off = 32; off > 0; off >>= 1) {
        s0 += __shfl_down(s0, off);
        s1 += __shfl_down(s1, off);
        s2 += __shfl_down(s2, off);
    }
    __shared__ double rd[4][3];
    int lane = threadIdx.x & 63, wv = threadIdx.x >> 6;
    if (lane == 0) { rd[wv][0] = s0; rd[wv][1] = s1; rd[wv][2] = s2; }
    __syncthreads();
    if (threadIdx.x == 0) {
        float ci = (float)((rd[0][0] + rd[1][0] + rd[2][0] + rd[3][0]) / 16.0);
        float co = (float)((rd[0][1] + rd[1][1] + rd[2][1] + rd[3][1]) / 16.0);
        float pr = (float)((rd[0][2] + rd[1][2] + rd[2][2] + rd[3][2]) / 16.0);
        out[0] = ci + co + pr;
        out[1] = ci;
        out[2] = co;
        out[3] = pr;
    }
}

extern "C" void kernel_launch(void* const* d_in, const int* in_sizes, int n_in,
                              void* d_out, int out_size, void* d_ws, size_t ws_size,
                              hipStream_t stream) {
    const float* conv_l = (const float*)d_in[0];
    const float* conv_m = (const float*)d_in[1];
    const float* conv_s = (const float*)d_in[2];
    const float* lab_s  = (const float*)d_in[3];
    const float* lab_m  = (const float*)d_in[4];
    const float* lab_l  = (const float*)d_in[5];
    const float* tb     = (const float*)d_in[6];
    float* pb  = (float*)d_ws;   // 2*NQ + NBCE floats
    float* out = (float*)d_out;

    yolo_main<<<NBLK, 256, 0, stream>>>(conv_l, conv_m, conv_s,
                                        lab_s, lab_m, lab_l, tb, pb);
    finalize_k<<<1, 256, 0, stream>>>(pb, out);
}